// Round 1
// baseline (709.408 us; speedup 1.0000x reference)
//
#include <hip/hip_runtime.h>

#define BATCH 8
#define NSEQ 1024
#define CDIM 512
#define TDIM 1536
#define NH 8
#define HD 64
#define QKV_SEC (BATCH * NH * NSEQ * HD) /* 4,194,304 floats per q/k/v section */

// ---------------------------------------------------------------------------
// Kernel 1: qkv = x @ w_qkv^T, scattered into q/k/v [b][h][n][hd] layout.
// NT GEMM: A [M=8192, K=512] row-major, B [D=1536, K=512] row-major.
// 64x64 tile, BK=32, 256 threads, 4x4 micro-tile, spread layout.
// ---------------------------------------------------------------------------
__global__ __launch_bounds__(256) void qkv_gemm_kernel(
    const float* __restrict__ x, const float* __restrict__ w,
    float* __restrict__ qkv) {
  __shared__ float As[64][32];  // reads are broadcast across tx -> no pad needed
  __shared__ float Bs[64][36];  // pad 36: 16B-aligned rows, 2-way max conflict
  const int tid = threadIdx.x;
  const int tx = tid & 15, ty = tid >> 4;
  const int d0 = blockIdx.x * 64;  // over 1536 output features
  const int m0 = blockIdx.y * 64;  // over B*N rows

  float acc[4][4] = {};

#pragma unroll 1
  for (int kb = 0; kb < CDIM; kb += 32) {
#pragma unroll
    for (int l = 0; l < 2; ++l) {
      int linear = tid + 256 * l;
      int row = linear >> 3;
      int c4 = (linear & 7) << 2;
      *reinterpret_cast<float4*>(&As[row][c4]) =
          *reinterpret_cast<const float4*>(&x[(size_t)(m0 + row) * CDIM + kb + c4]);
      *reinterpret_cast<float4*>(&Bs[row][c4]) =
          *reinterpret_cast<const float4*>(&w[(size_t)(d0 + row) * CDIM + kb + c4]);
    }
    __syncthreads();
#pragma unroll
    for (int d4 = 0; d4 < 8; ++d4) {
      float4 af[4], bf[4];
#pragma unroll
      for (int i = 0; i < 4; ++i)
        af[i] = *reinterpret_cast<const float4*>(&As[ty + 16 * i][d4 * 4]);
#pragma unroll
      for (int j = 0; j < 4; ++j)
        bf[j] = *reinterpret_cast<const float4*>(&Bs[tx + 16 * j][d4 * 4]);
#pragma unroll
      for (int i = 0; i < 4; ++i) {
#pragma unroll
        for (int j = 0; j < 4; ++j) {
          acc[i][j] += af[i].x * bf[j].x;
          acc[i][j] += af[i].y * bf[j].y;
          acc[i][j] += af[i].z * bf[j].z;
          acc[i][j] += af[i].w * bf[j].w;
        }
      }
    }
    __syncthreads();
  }

  // Scatter into q/k/v sections with [b][h][n][hd] layout.
#pragma unroll
  for (int i = 0; i < 4; ++i) {
    int m = m0 + ty + 16 * i;
    int b = m >> 10, n = m & 1023;
#pragma unroll
    for (int j = 0; j < 4; ++j) {
      int d = d0 + tx + 16 * j;
      int which = d >> 9;  // 0=q 1=k 2=v
      int c = d & 511;
      int h = c >> 6, dd = c & 63;
      qkv[(size_t)which * QKV_SEC +
          (((size_t)(b * NH + h) * NSEQ + n) * HD) + dd] = acc[i][j];
    }
  }
}

// ---------------------------------------------------------------------------
// Kernel 2: flash-style attention with spatial-decay bias.
// One block per (b, h, 64-row q-tile). 256 threads (4 waves).
// K tile is XOR-swizzled (float4 granule ^ (row&7)) so all 4 LDS arrays stay
// [64][64] -> exactly 64 KB static LDS.
// ---------------------------------------------------------------------------
__global__ __launch_bounds__(256) void attn_kernel(
    const float* __restrict__ qkv, const float* __restrict__ log_decay,
    float* __restrict__ aout /* [B*N][CDIM] */) {
  __shared__ float Qs[64][64];  // broadcast reads -> no pad
  __shared__ float Ks[64][64];  // XOR-swizzled
  __shared__ float Vs[64][64];  // reads indexed by tx in-row -> conflict-free
  __shared__ float Ps[64][64];  // broadcast reads -> no pad

  const int tid = threadIdx.x;
  const int tx = tid & 15, ty = tid >> 4;
  const int q0 = blockIdx.x * 64;
  const int h = blockIdx.y;
  const int b = blockIdx.z;

  const size_t base = ((size_t)(b * NH + h) * NSEQ) * HD;
  const float* Q = qkv + base;
  const float* K = qkv + (size_t)QKV_SEC + base;
  const float* V = qkv + 2 * (size_t)QKV_SEC + base;

  const float ldc = log_decay[h];
  const float decay = (ldc > 20.f) ? ldc : log1pf(__expf(ldc));  // softplus
  const float scale = 0.125f;  // hd^-0.5

  // Stage Q tile
#pragma unroll
  for (int l = 0; l < 4; ++l) {
    int linear = tid + 256 * l;
    int row = linear >> 4;
    int c4 = (linear & 15) << 2;
    *reinterpret_cast<float4*>(&Qs[row][c4]) =
        *reinterpret_cast<const float4*>(&Q[(size_t)(q0 + row) * HD + c4]);
  }

  float O[4][4] = {};
  float mrow[4], lrow[4];
#pragma unroll
  for (int i = 0; i < 4; ++i) { mrow[i] = -1e30f; lrow[i] = 0.f; }

  int qri[4], qci[4];
#pragma unroll
  for (int i = 0; i < 4; ++i) {
    int qr = q0 + ty + 16 * i;
    qri[i] = qr >> 5;
    qci[i] = qr & 31;
  }

#pragma unroll 1
  for (int c0 = 0; c0 < NSEQ; c0 += 64) {
    // Stage K (swizzled) and V chunks
#pragma unroll
    for (int l = 0; l < 4; ++l) {
      int linear = tid + 256 * l;
      int row = linear >> 4;
      int c4 = linear & 15;
      float4 kv = *reinterpret_cast<const float4*>(&K[(size_t)(c0 + row) * HD + (c4 << 2)]);
      *reinterpret_cast<float4*>(&Ks[row][(c4 ^ (row & 7)) << 2]) = kv;
      float4 vv = *reinterpret_cast<const float4*>(&V[(size_t)(c0 + row) * HD + (c4 << 2)]);
      *reinterpret_cast<float4*>(&Vs[row][c4 << 2]) = vv;
    }
    __syncthreads();  // covers Q staging on first iteration too

    // S = Q @ K^T  (64x64 mini-GEMM)
    float s[4][4] = {};
#pragma unroll
    for (int d4 = 0; d4 < 16; ++d4) {
      float4 qf[4], kf[4];
#pragma unroll
      for (int i = 0; i < 4; ++i)
        qf[i] = *reinterpret_cast<const float4*>(&Qs[ty + 16 * i][d4 * 4]);
#pragma unroll
      for (int j = 0; j < 4; ++j) {
        int r = tx + 16 * j;
        kf[j] = *reinterpret_cast<const float4*>(&Ks[r][(d4 ^ (r & 7)) << 2]);
      }
#pragma unroll
      for (int i = 0; i < 4; ++i) {
#pragma unroll
        for (int j = 0; j < 4; ++j) {
          s[i][j] += qf[i].x * kf[j].x;
          s[i][j] += qf[i].y * kf[j].y;
          s[i][j] += qf[i].z * kf[j].z;
          s[i][j] += qf[i].w * kf[j].w;
        }
      }
    }

    // bias + online softmax (per q-row: 16 lanes x 4 cols cover 64 k)
#pragma unroll
    for (int i = 0; i < 4; ++i) {
      float rowm = -1e30f;
#pragma unroll
      for (int j = 0; j < 4; ++j) {
        int kr = c0 + tx + 16 * j;
        int kri = kr >> 5, kci = kr & 31;
        int dd = abs(qri[i] - kri) + abs(qci[i] - kci);
        float t = s[i][j] * scale - decay * (float)dd;
        s[i][j] = t;
        rowm = fmaxf(rowm, t);
      }
#pragma unroll
      for (int msk = 1; msk <= 8; msk <<= 1)
        rowm = fmaxf(rowm, __shfl_xor(rowm, msk));
      float mnew = fmaxf(mrow[i], rowm);
      float alpha = __expf(mrow[i] - mnew);
      mrow[i] = mnew;
      float rs = 0.f;
#pragma unroll
      for (int j = 0; j < 4; ++j) {
        float p = __expf(s[i][j] - mnew);
        s[i][j] = p;
        rs += p;
      }
#pragma unroll
      for (int msk = 1; msk <= 8; msk <<= 1)
        rs += __shfl_xor(rs, msk);
      lrow[i] = lrow[i] * alpha + rs;
#pragma unroll
      for (int j = 0; j < 4; ++j) O[i][j] *= alpha;
      // stage P row-piece (same-wave producer/consumer; HW waitcnt orders it)
#pragma unroll
      for (int j = 0; j < 4; ++j) Ps[ty + 16 * i][tx + 16 * j] = s[i][j];
    }

    // O += P @ V  (64x64 mini-GEMM over k)
#pragma unroll
    for (int k4 = 0; k4 < 16; ++k4) {
      float4 pf[4];
#pragma unroll
      for (int i = 0; i < 4; ++i)
        pf[i] = *reinterpret_cast<const float4*>(&Ps[ty + 16 * i][k4 * 4]);
#pragma unroll
      for (int q = 0; q < 4; ++q) {
        int kk = k4 * 4 + q;
        float vv[4];
#pragma unroll
        for (int j = 0; j < 4; ++j) vv[j] = Vs[kk][tx + 16 * j];
#pragma unroll
        for (int i = 0; i < 4; ++i) {
          float p = (q == 0) ? pf[i].x : (q == 1) ? pf[i].y : (q == 2) ? pf[i].z : pf[i].w;
#pragma unroll
          for (int j = 0; j < 4; ++j) O[i][j] += p * vv[j];
        }
      }
    }
    __syncthreads();  // protect Ks/Vs before next chunk's staging
  }

  // epilogue: normalize and write [b][n][h*64+dd]
#pragma unroll
  for (int i = 0; i < 4; ++i) {
    float inv = 1.f / lrow[i];
    int n = q0 + ty + 16 * i;
    size_t rowbase = ((size_t)(b * NSEQ + n)) * CDIM + h * HD;
#pragma unroll
    for (int j = 0; j < 4; ++j) aout[rowbase + tx + 16 * j] = O[i][j] * inv;
  }
}

// ---------------------------------------------------------------------------
// Kernel 3: out = aout @ w_proj^T. Same structure as kernel 1, D=512.
// ---------------------------------------------------------------------------
__global__ __launch_bounds__(256) void proj_gemm_kernel(
    const float* __restrict__ a, const float* __restrict__ w,
    float* __restrict__ out) {
  __shared__ float As[64][32];
  __shared__ float Bs[64][36];
  const int tid = threadIdx.x;
  const int tx = tid & 15, ty = tid >> 4;
  const int d0 = blockIdx.x * 64;
  const int m0 = blockIdx.y * 64;

  float acc[4][4] = {};

#pragma unroll 1
  for (int kb = 0; kb < CDIM; kb += 32) {
#pragma unroll
    for (int l = 0; l < 2; ++l) {
      int linear = tid + 256 * l;
      int row = linear >> 3;
      int c4 = (linear & 7) << 2;
      *reinterpret_cast<float4*>(&As[row][c4]) =
          *reinterpret_cast<const float4*>(&a[(size_t)(m0 + row) * CDIM + kb + c4]);
      *reinterpret_cast<float4*>(&Bs[row][c4]) =
          *reinterpret_cast<const float4*>(&w[(size_t)(d0 + row) * CDIM + kb + c4]);
    }
    __syncthreads();
#pragma unroll
    for (int d4 = 0; d4 < 8; ++d4) {
      float4 af[4], bf[4];
#pragma unroll
      for (int i = 0; i < 4; ++i)
        af[i] = *reinterpret_cast<const float4*>(&As[ty + 16 * i][d4 * 4]);
#pragma unroll
      for (int j = 0; j < 4; ++j)
        bf[j] = *reinterpret_cast<const float4*>(&Bs[tx + 16 * j][d4 * 4]);
#pragma unroll
      for (int i = 0; i < 4; ++i) {
#pragma unroll
        for (int j = 0; j < 4; ++j) {
          acc[i][j] += af[i].x * bf[j].x;
          acc[i][j] += af[i].y * bf[j].y;
          acc[i][j] += af[i].z * bf[j].z;
          acc[i][j] += af[i].w * bf[j].w;
        }
      }
    }
    __syncthreads();
  }

#pragma unroll
  for (int i = 0; i < 4; ++i) {
    int m = m0 + ty + 16 * i;
#pragma unroll
    for (int j = 0; j < 4; ++j) {
      int d = d0 + tx + 16 * j;
      out[(size_t)m * CDIM + d] = acc[i][j];
    }
  }
}

extern "C" void kernel_launch(void* const* d_in, const int* in_sizes, int n_in,
                              void* d_out, int out_size, void* d_ws, size_t ws_size,
                              hipStream_t stream) {
  const float* x = (const float*)d_in[0];
  const float* w_qkv = (const float*)d_in[1];
  const float* w_proj = (const float*)d_in[2];
  const float* log_decay = (const float*)d_in[3];
  // d_in[4]/d_in[5] are H=32, W=32 (hardcoded in the kernels)

  float* ws = (float*)d_ws;
  float* qkv = ws;                          // 3 * 4,194,304 floats (48 MB)
  float* aout = ws + 3 * (size_t)QKV_SEC;   // 4,194,304 floats (16 MB)
  float* out = (float*)d_out;

  dim3 blk(256);
  qkv_gemm_kernel<<<dim3(TDIM / 64, (BATCH * NSEQ) / 64), blk, 0, stream>>>(
      x, w_qkv, qkv);
  attn_kernel<<<dim3(NSEQ / 64, NH, BATCH), blk, 0, stream>>>(
      qkv, log_decay, aout);
  proj_gemm_kernel<<<dim3(CDIM / 64, (BATCH * NSEQ) / 64), blk, 0, stream>>>(
      aout, w_proj, out);
}

// Round 2
// 183.990 us; speedup vs baseline: 3.8557x; 3.8557x over previous
//
#include <hip/hip_runtime.h>
#include <stdint.h>

typedef _Float16 f16;
typedef _Float16 f16x8 __attribute__((ext_vector_type(8)));
typedef _Float16 f16x4 __attribute__((ext_vector_type(4)));
typedef float f32x4 __attribute__((ext_vector_type(4)));

#define MROWS 8192
#define KDIM 512
#define NSEQ 1024
#define NH 8

// ---------------------------------------------------------------------------
// global -> LDS async copy, 16B per lane. LDS dest = wave-uniform base +
// lane*16 (HW); global src is per-lane. Swizzled LDS layouts are achieved by
// pre-swizzling the global source address (m173 pattern).
// ---------------------------------------------------------------------------
__device__ __forceinline__ void gload16(void* lds, const void* g) {
  __builtin_amdgcn_global_load_lds(
      (const __attribute__((address_space(1))) unsigned*)g,
      (__attribute__((address_space(3))) unsigned*)lds, 16, 0, 0);
}

__device__ __forceinline__ f32x4 mfma16(f16x8 a, f16x8 b, f32x4 c) {
  return __builtin_amdgcn_mfma_f32_16x16x32_f16(a, b, c, 0, 0, 0);
}

// ---------------------------------------------------------------------------
// fp32 -> f16 convert of x, w_qkv, w_proj
// ---------------------------------------------------------------------------
__global__ __launch_bounds__(256) void cvt_kernel(
    const float* __restrict__ x, const float* __restrict__ wq,
    const float* __restrict__ wp, f16* __restrict__ x16,
    f16* __restrict__ wq16, f16* __restrict__ wp16) {
  int t = blockIdx.x * 256 + threadIdx.x;
  int stride = gridDim.x * 256;
  for (int i = t; i < (MROWS * KDIM) / 4; i += stride) {
    float4 v = ((const float4*)x)[i];
    f16x4 o = {(f16)v.x, (f16)v.y, (f16)v.z, (f16)v.w};
    ((f16x4*)x16)[i] = o;
  }
  for (int i = t; i < (3 * KDIM * KDIM) / 4; i += stride) {
    float4 v = ((const float4*)wq)[i];
    f16x4 o = {(f16)v.x, (f16)v.y, (f16)v.z, (f16)v.w};
    ((f16x4*)wq16)[i] = o;
  }
  for (int i = t; i < (KDIM * KDIM) / 4; i += stride) {
    float4 v = ((const float4*)wp)[i];
    f16x4 o = {(f16)v.x, (f16)v.y, (f16)v.z, (f16)v.w};
    ((f16x4*)wp16)[i] = o;
  }
}

// ---------------------------------------------------------------------------
// Shared NT-GEMM main loop: C[128x128] tile, BK=64, 256 threads (4 waves),
// each wave one 64x64 quadrant = 4x4 grid of 16x16x32 f16 MFMAs.
// A [M][512], B [N][512] row-major f16 (both K-contiguous).
// LDS rows are 128B; fragment ds_read_b128 uses XOR slot-swizzle
// (slot ^ (row&7)), staged via pre-swizzled global source.
// ---------------------------------------------------------------------------
__device__ __forceinline__ void gemm_mainloop(
    const f16* __restrict__ A, const f16* __restrict__ B, int m0, int n0,
    f16* As, f16* Bs, f32x4 (&acc)[4][4]) {
  const int tid = threadIdx.x;
  const int w = tid >> 6, l = tid & 63;
  const int wr = w >> 1, wc = w & 1;
  const int lrow = l & 15, lk = l >> 4;
  const int srow = l >> 3, sslot = l & 7;
  const int scol = ((sslot ^ srow) << 3);  // pre-swizzled source col (f16 units)

#pragma unroll 1
  for (int kb = 0; kb < KDIM; kb += 64) {
#pragma unroll
    for (int j = 0; j < 4; ++j) {
      int i = w * 4 + j;
      int row = i * 8 + srow;
      gload16(As + i * 512, A + (size_t)(m0 + row) * KDIM + kb + scol);
      gload16(Bs + i * 512, B + (size_t)(n0 + row) * KDIM + kb + scol);
    }
    __syncthreads();
#pragma unroll
    for (int kk = 0; kk < 2; ++kk) {
      int slotbase = kk * 4 + lk;
      f16x8 af[4], bf[4];
#pragma unroll
      for (int mi = 0; mi < 4; ++mi) {
        int row = wr * 64 + mi * 16 + lrow;
        af[mi] = *(const f16x8*)(As + row * 64 + ((slotbase ^ (row & 7)) << 3));
      }
#pragma unroll
      for (int nj = 0; nj < 4; ++nj) {
        int row = wc * 64 + nj * 16 + lrow;
        bf[nj] = *(const f16x8*)(Bs + row * 64 + ((slotbase ^ (row & 7)) << 3));
      }
#pragma unroll
      for (int mi = 0; mi < 4; ++mi)
#pragma unroll
        for (int nj = 0; nj < 4; ++nj)
          acc[mi][nj] = mfma16(af[mi], bf[nj], acc[mi][nj]);
    }
    __syncthreads();
  }
}

// ---------------------------------------------------------------------------
// Kernel: qkv = x16 @ wq16^T, scattered as f16 into q/k/v [b][h][n][64].
// ---------------------------------------------------------------------------
__global__ __launch_bounds__(256) void qkv_gemm(
    const f16* __restrict__ x16, const f16* __restrict__ wq16,
    f16* __restrict__ q16, f16* __restrict__ k16, f16* __restrict__ v16) {
  __shared__ f16 As[128 * 64];
  __shared__ f16 Bs[128 * 64];
  f32x4 acc[4][4];
#pragma unroll
  for (int i = 0; i < 4; ++i)
#pragma unroll
    for (int j = 0; j < 4; ++j) acc[i][j] = (f32x4){0.f, 0.f, 0.f, 0.f};

  const int m0 = blockIdx.y * 128, n0 = blockIdx.x * 128;
  gemm_mainloop(x16, wq16, m0, n0, As, Bs, acc);

  const int tid = threadIdx.x;
  const int w = tid >> 6, l = tid & 63;
  const int wr = w >> 1, wc = w & 1;
#pragma unroll
  for (int mi = 0; mi < 4; ++mi) {
#pragma unroll
    for (int rr = 0; rr < 4; ++rr) {
      int m = m0 + wr * 64 + mi * 16 + (l >> 4) * 4 + rr;
      int b = m >> 10, n = m & 1023;
#pragma unroll
      for (int nj = 0; nj < 4; ++nj) {
        int d = n0 + wc * 64 + nj * 16 + (l & 15);
        int which = d >> 9, c = d & 511;
        int h = c >> 6, dd = c & 63;
        f16* dst = (which == 0) ? q16 : (which == 1) ? k16 : v16;
        dst[(((size_t)(b * NH + h)) * NSEQ + n) * 64 + dd] = (f16)acc[mi][nj][rr];
      }
    }
  }
}

// ---------------------------------------------------------------------------
// Kernel: out = a16 @ wp16^T (fp32 out).
// ---------------------------------------------------------------------------
__global__ __launch_bounds__(256) void proj_gemm(
    const f16* __restrict__ a16, const f16* __restrict__ wp16,
    float* __restrict__ out) {
  __shared__ f16 As[128 * 64];
  __shared__ f16 Bs[128 * 64];
  f32x4 acc[4][4];
#pragma unroll
  for (int i = 0; i < 4; ++i)
#pragma unroll
    for (int j = 0; j < 4; ++j) acc[i][j] = (f32x4){0.f, 0.f, 0.f, 0.f};

  const int m0 = blockIdx.y * 128, n0 = blockIdx.x * 128;
  gemm_mainloop(a16, wp16, m0, n0, As, Bs, acc);

  const int tid = threadIdx.x;
  const int w = tid >> 6, l = tid & 63;
  const int wr = w >> 1, wc = w & 1;
#pragma unroll
  for (int mi = 0; mi < 4; ++mi) {
#pragma unroll
    for (int rr = 0; rr < 4; ++rr) {
      int m = m0 + wr * 64 + mi * 16 + (l >> 4) * 4 + rr;
#pragma unroll
      for (int nj = 0; nj < 4; ++nj) {
        int d = n0 + wc * 64 + nj * 16 + (l & 15);
        out[(size_t)m * KDIM + d] = acc[mi][nj][rr];
      }
    }
  }
}

// ---------------------------------------------------------------------------
// MFMA flash attention with spatial-decay bias.
// Block = (128 q-rows) x (b,h); 256 threads = 4 waves, each wave 32 q-rows.
// Q in registers; K swizzled in LDS; V staged linear then transposed once per
// kv-tile into swizzled Vt; P through swizzled LDS. 2 barriers per kv-tile.
// ---------------------------------------------------------------------------
__global__ __launch_bounds__(256) void attn_f16(
    const f16* __restrict__ q16, const f16* __restrict__ k16,
    const f16* __restrict__ v16, const float* __restrict__ log_decay,
    f16* __restrict__ aout) {
  __shared__ f16 Ks[64 * 64];
  __shared__ f16 Vs[64 * 64];
  __shared__ f16 Vt[64 * 64];
  __shared__ f16 Ps[128 * 64];

  const int tid = threadIdx.x;
  const int w = tid >> 6, l = tid & 63;
  const int q0 = blockIdx.x * 128;
  const int h = blockIdx.y, b = blockIdx.z;
  const size_t base = ((size_t)(b * NH + h)) * NSEQ * 64;

  const float decay = log1pf(__expf(log_decay[h]));  // softplus
  const float scale = 0.125f;                        // hd^-0.5

  const int lrow = l & 15, lk = l >> 4;
  const int srow = l >> 3, sslot = l & 7;
  const int scol = ((sslot ^ srow) << 3);

  // Q fragments in registers: wave w owns q-rows [q0+32w, q0+32w+32)
  f16x8 qf[2][2];
#pragma unroll
  for (int mi = 0; mi < 2; ++mi)
#pragma unroll
    for (int kk = 0; kk < 2; ++kk) {
      int row = q0 + w * 32 + mi * 16 + lrow;
      qf[mi][kk] = *(const f16x8*)(q16 + base + (size_t)row * 64 + kk * 32 + lk * 8);
    }

  f32x4 O[2][4];
  float mrow[2][4], lsum[2][4];
#pragma unroll
  for (int mi = 0; mi < 2; ++mi) {
#pragma unroll
    for (int dj = 0; dj < 4; ++dj) O[mi][dj] = (f32x4){0.f, 0.f, 0.f, 0.f};
#pragma unroll
    for (int rr = 0; rr < 4; ++rr) { mrow[mi][rr] = -1e30f; lsum[mi][rr] = 0.f; }
  }

  int qr_[2][4], qc_[2][4];
#pragma unroll
  for (int mi = 0; mi < 2; ++mi)
#pragma unroll
    for (int rr = 0; rr < 4; ++rr) {
      int qn = q0 + w * 32 + mi * 16 + lk * 4 + rr;
      qr_[mi][rr] = qn >> 5;
      qc_[mi][rr] = qn & 31;
    }

#pragma unroll 1
  for (int c0 = 0; c0 < NSEQ; c0 += 64) {
    // ---- stage K (swizzled source) and V (linear), 2 gloads each per wave
#pragma unroll
    for (int j = 0; j < 2; ++j) {
      int i = w * 2 + j;
      int row = i * 8 + srow;
      gload16(Ks + i * 512, k16 + base + (size_t)(c0 + row) * 64 + scol);
      gload16(Vs + i * 512, v16 + base + (size_t)(c0 + row) * 64 + sslot * 8);
    }
    __syncthreads();  // staging visible (also orders prev-iter PV before overwrite)

    // ---- transpose Vs[kv][d] -> Vt[d][kv] (swizzled rows of 128B)
    {
      int d = tid & 63, kq = tid >> 6;  // kv block of 16
      f16 tmp[16];
#pragma unroll
      for (int i = 0; i < 16; ++i) tmp[i] = Vs[(kq * 16 + i) * 64 + d];
#pragma unroll
      for (int hh = 0; hh < 2; ++hh) {
        f16x8 vv;
#pragma unroll
        for (int e = 0; e < 8; ++e) vv[e] = tmp[hh * 8 + e];
        int slot = kq * 2 + hh;
        *(f16x8*)(Vt + d * 64 + ((slot ^ (d & 7)) << 3)) = vv;
      }
    }

    // ---- S = Q @ K^T  (wave: 32q x 64kv)
    f32x4 s[2][4];
#pragma unroll
    for (int mi = 0; mi < 2; ++mi)
#pragma unroll
      for (int nj = 0; nj < 4; ++nj) s[mi][nj] = (f32x4){0.f, 0.f, 0.f, 0.f};
#pragma unroll
    for (int kk = 0; kk < 2; ++kk) {
      int slotbase = kk * 4 + lk;
      f16x8 kf[4];
#pragma unroll
      for (int nj = 0; nj < 4; ++nj) {
        int row = nj * 16 + lrow;
        kf[nj] = *(const f16x8*)(Ks + row * 64 + ((slotbase ^ (row & 7)) << 3));
      }
#pragma unroll
      for (int mi = 0; mi < 2; ++mi)
#pragma unroll
        for (int nj = 0; nj < 4; ++nj)
          s[mi][nj] = mfma16(qf[mi][kk], kf[nj], s[mi][nj]);
    }

    // ---- bias + online softmax; write P (f16) to swizzled Ps
    int kr_[4], kc_[4];
#pragma unroll
    for (int nj = 0; nj < 4; ++nj) {
      int kn = c0 + nj * 16 + lrow;
      kr_[nj] = kn >> 5;
      kc_[nj] = kn & 31;
    }
#pragma unroll
    for (int mi = 0; mi < 2; ++mi) {
#pragma unroll
      for (int rr = 0; rr < 4; ++rr) {
        float sv[4];
        float mx = -1e30f;
#pragma unroll
        for (int nj = 0; nj < 4; ++nj) {
          int da = qr_[mi][rr] - kr_[nj]; da = (da < 0) ? -da : da;
          int db = qc_[mi][rr] - kc_[nj]; db = (db < 0) ? -db : db;
          float t = s[mi][nj][rr] * scale - decay * (float)(da + db);
          sv[nj] = t;
          mx = fmaxf(mx, t);
        }
#pragma unroll
        for (int msk = 1; msk <= 8; msk <<= 1)
          mx = fmaxf(mx, __shfl_xor(mx, msk));
        float mnew = fmaxf(mrow[mi][rr], mx);
        float al = __expf(mrow[mi][rr] - mnew);
        mrow[mi][rr] = mnew;
        float rs = 0.f;
        int qrl = w * 32 + mi * 16 + lk * 4 + rr;
#pragma unroll
        for (int nj = 0; nj < 4; ++nj) {
          float p = __expf(sv[nj] - mnew);
          rs += p;
          int kvl = nj * 16 + lrow;
          Ps[qrl * 64 + ((((kvl >> 3) ^ (qrl & 7))) << 3) + (kvl & 7)] = (f16)p;
        }
#pragma unroll
        for (int msk = 1; msk <= 8; msk <<= 1) rs += __shfl_xor(rs, msk);
        lsum[mi][rr] = lsum[mi][rr] * al + rs;
#pragma unroll
        for (int dj = 0; dj < 4; ++dj) O[mi][dj][rr] *= al;
      }
    }
    __syncthreads();  // Vt + Ps visible before PV; staging of next iter is after

    // ---- O += P @ V  (A-frags from Ps, B-frags from Vt; all clean b128)
#pragma unroll
    for (int kk = 0; kk < 2; ++kk) {
      int slotbase = kk * 4 + lk;
      f16x8 pa[2], vb[4];
#pragma unroll
      for (int mi = 0; mi < 2; ++mi) {
        int row = w * 32 + mi * 16 + lrow;
        pa[mi] = *(const f16x8*)(Ps + row * 64 + ((slotbase ^ (row & 7)) << 3));
      }
#pragma unroll
      for (int dj = 0; dj < 4; ++dj) {
        int d = dj * 16 + lrow;
        vb[dj] = *(const f16x8*)(Vt + d * 64 + ((slotbase ^ (d & 7)) << 3));
      }
#pragma unroll
      for (int mi = 0; mi < 2; ++mi)
#pragma unroll
        for (int dj = 0; dj < 4; ++dj)
          O[mi][dj] = mfma16(pa[mi], vb[dj], O[mi][dj]);
    }
  }

  // ---- epilogue: normalize, write aout [b*1024+n][h*64+d] as f16
#pragma unroll
  for (int mi = 0; mi < 2; ++mi) {
#pragma unroll
    for (int rr = 0; rr < 4; ++rr) {
      float inv = 1.f / lsum[mi][rr];
      int qn = q0 + w * 32 + mi * 16 + lk * 4 + rr;
      size_t rowbase = ((size_t)(b * NSEQ + qn)) * KDIM + h * 64;
#pragma unroll
      for (int dj = 0; dj < 4; ++dj)
        aout[rowbase + dj * 16 + lrow] = (f16)(O[mi][dj][rr] * inv);
    }
  }
}

extern "C" void kernel_launch(void* const* d_in, const int* in_sizes, int n_in,
                              void* d_out, int out_size, void* d_ws, size_t ws_size,
                              hipStream_t stream) {
  const float* x = (const float*)d_in[0];
  const float* w_qkv = (const float*)d_in[1];
  const float* w_proj = (const float*)d_in[2];
  const float* log_decay = (const float*)d_in[3];

  f16* ws = (f16*)d_ws;
  f16* x16 = ws;                      // 4,194,304
  f16* wq16 = x16 + (size_t)MROWS * KDIM;        // 786,432
  f16* wp16 = wq16 + (size_t)3 * KDIM * KDIM;    // 262,144
  f16* q16 = wp16 + (size_t)KDIM * KDIM;         // 4,194,304
  f16* k16 = q16 + (size_t)MROWS * KDIM;
  f16* v16 = k16 + (size_t)MROWS * KDIM;
  f16* a16 = v16 + (size_t)MROWS * KDIM;

  cvt_kernel<<<1024, 256, 0, stream>>>(x, w_qkv, w_proj, x16, wq16, wp16);
  qkv_gemm<<<dim3(12, 64), 256, 0, stream>>>(x16, wq16, q16, k16, v16);
  attn_f16<<<dim3(8, NH, 8), 256, 0, stream>>>(q16, k16, v16, log_decay, a16);
  proj_gemm<<<dim3(4, 64), 256, 0, stream>>>(a16, wp16, (float*)d_out);
}

// Round 4
// 155.813 us; speedup vs baseline: 4.5529x; 1.1808x over previous
//
#include <hip/hip_runtime.h>
#include <stdint.h>

typedef _Float16 f16;
typedef _Float16 f16x8 __attribute__((ext_vector_type(8)));
typedef _Float16 f16x4 __attribute__((ext_vector_type(4)));
typedef _Float16 f16x2 __attribute__((ext_vector_type(2)));
typedef float f32x4 __attribute__((ext_vector_type(4)));

#define MROWS 8192
#define KDIM 512
#define NSEQ 1024
#define NH 8

__device__ __forceinline__ void gload16(void* lds, const void* g) {
  __builtin_amdgcn_global_load_lds(
      (const __attribute__((address_space(1))) unsigned*)g,
      (__attribute__((address_space(3))) unsigned*)lds, 16, 0, 0);
}

__device__ __forceinline__ f32x4 mfma16(f16x8 a, f16x8 b, f32x4 c) {
  return __builtin_amdgcn_mfma_f32_16x16x32_f16(a, b, c, 0, 0, 0);
}

// ---------------------------------------------------------------------------
// fp32 -> f16 convert of x, w_qkv, w_proj
// ---------------------------------------------------------------------------
__global__ __launch_bounds__(256) void cvt_kernel(
    const float* __restrict__ x, const float* __restrict__ wq,
    const float* __restrict__ wp, f16* __restrict__ x16,
    f16* __restrict__ wq16, f16* __restrict__ wp16) {
  int t = blockIdx.x * 256 + threadIdx.x;
  int stride = gridDim.x * 256;
  for (int i = t; i < (MROWS * KDIM) / 4; i += stride) {
    float4 v = ((const float4*)x)[i];
    f16x4 o = {(f16)v.x, (f16)v.y, (f16)v.z, (f16)v.w};
    ((f16x4*)x16)[i] = o;
  }
  for (int i = t; i < (3 * KDIM * KDIM) / 4; i += stride) {
    float4 v = ((const float4*)wq)[i];
    f16x4 o = {(f16)v.x, (f16)v.y, (f16)v.z, (f16)v.w};
    ((f16x4*)wq16)[i] = o;
  }
  for (int i = t; i < (KDIM * KDIM) / 4; i += stride) {
    float4 v = ((const float4*)wp)[i];
    f16x4 o = {(f16)v.x, (f16)v.y, (f16)v.z, (f16)v.w};
    ((f16x4*)wp16)[i] = o;
  }
}

// ---------------------------------------------------------------------------
// Double-buffered NT-GEMM main loop: C[128x128], BK=64, 256 threads (4 waves),
// wave = one 64x64 quadrant = 4x4 grid of 16x16x32 f16 MFMAs.
// Counted vmcnt(8) keeps next tile's global_load_lds in flight across the raw
// s_barrier (no compiler vmcnt(0) drain).
// Race analysis: staging (vmem->LDS) completion is ordered by the explicit
// vmcnt wait BEFORE bar1, uniformly across waves. All ds_read results feed
// MFMAs, whose operand waits drain lgkmcnt before each wave reaches a
// barrier, so no cross-wave WAR hazard on the LDS buffers. The asm "memory"
// clobbers block LDS-read motion across barriers (gload_lds writes are
// compiler-invisible).
// ---------------------------------------------------------------------------
__device__ __forceinline__ void gemm_mainloop_db(
    const f16* __restrict__ A, const f16* __restrict__ B, int m0, int n0,
    f16* As0, f16* As1, f16* Bs0, f16* Bs1, f32x4 (&acc)[4][4]) {
  const int tid = threadIdx.x;
  const int w = tid >> 6, l = tid & 63;
  const int wr = w >> 1, wc = w & 1;
  const int lrow = l & 15, lk = l >> 4;
  const int srow = l >> 3, sslot = l & 7;
  const int scol = ((sslot ^ srow) << 3);  // pre-swizzled source col
  const int NT = KDIM / 64;

  auto STAGE = [&](int bb, int kb) {
    f16* Ad = bb ? As1 : As0;
    f16* Bd = bb ? Bs1 : Bs0;
#pragma unroll
    for (int j = 0; j < 4; ++j) {
      int i = w * 4 + j;
      int row = i * 8 + srow;
      gload16(Ad + i * 512, A + (size_t)(m0 + row) * KDIM + kb + scol);
      gload16(Bd + i * 512, B + (size_t)(n0 + row) * KDIM + kb + scol);
    }
  };

  STAGE(0, 0);
#pragma unroll 1
  for (int t = 0; t < NT; ++t) {
    if (t + 1 < NT) {
      STAGE((t + 1) & 1, (t + 1) * 64);
      asm volatile("s_waitcnt vmcnt(8)" ::: "memory");
    } else {
      asm volatile("s_waitcnt vmcnt(0)" ::: "memory");
    }
    __builtin_amdgcn_s_barrier();  // bar1: buf[t&1] fully staged
    const f16* Asr = (t & 1) ? As1 : As0;
    const f16* Bsr = (t & 1) ? Bs1 : Bs0;
#pragma unroll
    for (int kk = 0; kk < 2; ++kk) {
      int slotbase = kk * 4 + lk;
      f16x8 af[4], bf[4];
#pragma unroll
      for (int mi = 0; mi < 4; ++mi) {
        int row = wr * 64 + mi * 16 + lrow;
        af[mi] = *(const f16x8*)(Asr + row * 64 + ((slotbase ^ (row & 7)) << 3));
      }
#pragma unroll
      for (int nj = 0; nj < 4; ++nj) {
        int row = wc * 64 + nj * 16 + lrow;
        bf[nj] = *(const f16x8*)(Bsr + row * 64 + ((slotbase ^ (row & 7)) << 3));
      }
#pragma unroll
      for (int mi = 0; mi < 4; ++mi)
#pragma unroll
        for (int nj = 0; nj < 4; ++nj)
          acc[mi][nj] = mfma16(af[mi], bf[nj], acc[mi][nj]);
    }
    __builtin_amdgcn_s_barrier();  // bar2: reads of buf[t&1] done
  }
}

// ---------------------------------------------------------------------------
// qkv = x16 @ wq16^T, scattered as f16 into q/k/v [b][h][n][64].
// ---------------------------------------------------------------------------
__global__ __launch_bounds__(256, 2) void qkv_gemm(
    const f16* __restrict__ x16, const f16* __restrict__ wq16,
    f16* __restrict__ q16, f16* __restrict__ k16, f16* __restrict__ v16) {
  __shared__ f16 As0[128 * 64], As1[128 * 64];
  __shared__ f16 Bs0[128 * 64], Bs1[128 * 64];
  f32x4 acc[4][4];
#pragma unroll
  for (int i = 0; i < 4; ++i)
#pragma unroll
    for (int j = 0; j < 4; ++j) acc[i][j] = (f32x4){0.f, 0.f, 0.f, 0.f};

  const int m0 = blockIdx.y * 128, n0 = blockIdx.x * 128;
  gemm_mainloop_db(x16, wq16, m0, n0, As0, As1, Bs0, Bs1, acc);

  const int tid = threadIdx.x;
  const int w = tid >> 6, l = tid & 63;
  const int wr = w >> 1, wc = w & 1;
#pragma unroll
  for (int mi = 0; mi < 4; ++mi) {
#pragma unroll
    for (int rr = 0; rr < 4; ++rr) {
      int m = m0 + wr * 64 + mi * 16 + (l >> 4) * 4 + rr;
      int b = m >> 10, n = m & 1023;
#pragma unroll
      for (int nj = 0; nj < 4; ++nj) {
        int d = n0 + wc * 64 + nj * 16 + (l & 15);
        int which = d >> 9, c = d & 511;
        int h = c >> 6, dd = c & 63;
        f16* dst = (which == 0) ? q16 : (which == 1) ? k16 : v16;
        dst[(((size_t)(b * NH + h)) * NSEQ + n) * 64 + dd] = (f16)acc[mi][nj][rr];
      }
    }
  }
}

// ---------------------------------------------------------------------------
// out = a16 @ wp16^T (fp32 out).
// ---------------------------------------------------------------------------
__global__ __launch_bounds__(256, 2) void proj_gemm(
    const f16* __restrict__ a16, const f16* __restrict__ wp16,
    float* __restrict__ out) {
  __shared__ f16 As0[128 * 64], As1[128 * 64];
  __shared__ f16 Bs0[128 * 64], Bs1[128 * 64];
  f32x4 acc[4][4];
#pragma unroll
  for (int i = 0; i < 4; ++i)
#pragma unroll
    for (int j = 0; j < 4; ++j) acc[i][j] = (f32x4){0.f, 0.f, 0.f, 0.f};

  const int m0 = blockIdx.y * 128, n0 = blockIdx.x * 128;
  gemm_mainloop_db(a16, wp16, m0, n0, As0, As1, Bs0, Bs1, acc);

  const int tid = threadIdx.x;
  const int w = tid >> 6, l = tid & 63;
  const int wr = w >> 1, wc = w & 1;
#pragma unroll
  for (int mi = 0; mi < 4; ++mi) {
#pragma unroll
    for (int rr = 0; rr < 4; ++rr) {
      int m = m0 + wr * 64 + mi * 16 + (l >> 4) * 4 + rr;
#pragma unroll
      for (int nj = 0; nj < 4; ++nj) {
        int d = n0 + wc * 64 + nj * 16 + (l & 15);
        out[(size_t)m * KDIM + d] = acc[mi][nj][rr];
      }
    }
  }
}

// ---------------------------------------------------------------------------
// MFMA flash attention, swapped-QK^T softmax.
// Block = 128 q-rows x (b,h); 4 waves x 32 q-rows. Grid 512 = 2 blocks/CU.
// S^T = mfma(K,Q): lane's 16 scores (4 mi x 4 rr) all belong to q = njq*16 +
// (lane&15) -> row reduce = in-lane tree + shfl_xor(16,32). P written as b64.
// K/V double-buffered via counted vmcnt(4) + raw barriers (2/tile):
//   bar1: buf[cur] staged (vmcnt wait precedes, uniform across waves);
//         prev-iter PV reads done (consumed by MFMAs) -> transpose may
//         overwrite Vt, softmax may overwrite Ps.
//   bar2: preceded by explicit lgkmcnt(0) so Vt/Ps ds_writes are VISIBLE
//         (raw s_barrier does not drain lgkmcnt!); Ks/Vs[cur] reads complete
//         -> next-iter staging may overwrite the other buffer.
// ---------------------------------------------------------------------------
__device__ __forceinline__ int swzd(int d) {  // Vt row swizzle
  return ((d >> 1) & 3) | ((d & 1) << 2);
}

__global__ __launch_bounds__(256, 2) void attn_f16(
    const f16* __restrict__ q16, const f16* __restrict__ k16,
    const f16* __restrict__ v16, const float* __restrict__ log_decay,
    f16* __restrict__ aout) {
  __shared__ f16 Ks0[64 * 64], Ks1[64 * 64];
  __shared__ f16 Vs0[64 * 64], Vs1[64 * 64];
  __shared__ f16 Vt[64 * 64];
  __shared__ f16 Ps[128 * 64];

  const int tid = threadIdx.x;
  const int w = tid >> 6, l = tid & 63;
  const int lrow = l & 15, lk = l >> 4;
  const int srow = l >> 3, sslot = l & 7;
  const int scol = ((sslot ^ srow) << 3);
  const int q0 = blockIdx.x * 128;
  const int h = blockIdx.y, b = blockIdx.z;
  const size_t base = ((size_t)(b * NH + h)) * NSEQ * 64;

  const float decay = log1pf(__expf(log_decay[h]));  // softplus

  // Q fragments (B-operand rows), pre-scaled by hd^-0.5 = 0.125
  f16x8 qf[2][2];
#pragma unroll
  for (int njq = 0; njq < 2; ++njq)
#pragma unroll
    for (int kk = 0; kk < 2; ++kk) {
      int row = q0 + w * 32 + njq * 16 + lrow;
      f16x8 v = *(const f16x8*)(q16 + base + (size_t)row * 64 + kk * 32 + lk * 8);
#pragma unroll
      for (int e = 0; e < 8; ++e) v[e] = v[e] * (f16)0.125f;
      qf[njq][kk] = v;
    }

  int qr_[2], qc_[2];
#pragma unroll
  for (int njq = 0; njq < 2; ++njq) {
    int qn = q0 + w * 32 + njq * 16 + lrow;
    qr_[njq] = qn >> 5;
    qc_[njq] = qn & 31;
  }

  f32x4 O[2][4];
#pragma unroll
  for (int njq = 0; njq < 2; ++njq)
#pragma unroll
    for (int dj = 0; dj < 4; ++dj) O[njq][dj] = (f32x4){0.f, 0.f, 0.f, 0.f};
  float mrow[2] = {-1e30f, -1e30f}, lsum[2] = {0.f, 0.f};

  auto STAGE_T = [&](int bb, int c0) {
    f16* Kd = bb ? Ks1 : Ks0;
    f16* Vd = bb ? Vs1 : Vs0;
#pragma unroll
    for (int j = 0; j < 2; ++j) {
      int i = w * 2 + j;
      int row = i * 8 + srow;
      gload16(Kd + i * 512, k16 + base + (size_t)(c0 + row) * 64 + scol);
      gload16(Vd + i * 512, v16 + base + (size_t)(c0 + row) * 64 + (sslot << 3));
    }
  };

  STAGE_T(0, 0);
#pragma unroll 1
  for (int t = 0; t < NSEQ / 64; ++t) {
    const int c0 = t * 64;
    const int cur = t & 1;
    if (t + 1 < NSEQ / 64) {
      STAGE_T(cur ^ 1, c0 + 64);
      asm volatile("s_waitcnt vmcnt(4)" ::: "memory");
    } else {
      asm volatile("s_waitcnt vmcnt(0)" ::: "memory");
    }
    __builtin_amdgcn_s_barrier();  // bar1

    // ---- transpose Vs[cur][kv][d] -> Vt[d][kv] (swizzled)
    {
      const f16* vsrc = cur ? Vs1 : Vs0;
      int dd = (tid & 31) * 2;
      int kq = tid >> 5;
      f16x8 v0, v1;
#pragma unroll
      for (int i = 0; i < 8; ++i) {
        f16x2 pr = *(const f16x2*)(vsrc + (size_t)(kq * 8 + i) * 64 + dd);
        v0[i] = pr.x;
        v1[i] = pr.y;
      }
      *(f16x8*)(Vt + (size_t)dd * 64 + ((kq ^ swzd(dd)) << 3)) = v0;
      *(f16x8*)(Vt + (size_t)(dd + 1) * 64 + ((kq ^ swzd(dd + 1)) << 3)) = v1;
    }

    // ---- S^T = K @ Q^T (16 MFMA); s[mi][njq]: lane q = njq*16+lrow,
    //      kv = c0 + mi*16 + lk*4 + rr
    const f16* ksrc = cur ? Ks1 : Ks0;
    f32x4 s[4][2];
#pragma unroll
    for (int mi = 0; mi < 4; ++mi)
#pragma unroll
      for (int njq = 0; njq < 2; ++njq) s[mi][njq] = (f32x4){0.f, 0.f, 0.f, 0.f};
#pragma unroll
    for (int kk = 0; kk < 2; ++kk) {
      int slotbase = kk * 4 + lk;
#pragma unroll
      for (int mi = 0; mi < 4; ++mi) {
        int row = mi * 16 + lrow;
        f16x8 kf = *(const f16x8*)(ksrc + row * 64 + ((slotbase ^ (row & 7)) << 3));
#pragma unroll
        for (int njq = 0; njq < 2; ++njq)
          s[mi][njq] = mfma16(kf, qf[njq][kk], s[mi][njq]);
      }
    }

    // ---- bias + online softmax (per njq); P -> Ps (b64 writes)
    float al[2];
#pragma unroll
    for (int njq = 0; njq < 2; ++njq) {
      float mx = -1e30f;
#pragma unroll
      for (int mi = 0; mi < 4; ++mi) {
        int kvb = c0 + mi * 16 + lk * 4;
        int krb = kvb >> 5, kcb = kvb & 31;
        float dr = (float)__builtin_abs(qr_[njq] - krb);
        int t1 = qc_[njq] - kcb;
#pragma unroll
        for (int rr = 0; rr < 4; ++rr) {
          float dc = (float)__builtin_abs(t1 - rr);
          float tt = fmaf(-decay, dr + dc, s[mi][njq][rr]);
          s[mi][njq][rr] = tt;
          mx = fmaxf(mx, tt);
        }
      }
      mx = fmaxf(mx, __shfl_xor(mx, 16));
      mx = fmaxf(mx, __shfl_xor(mx, 32));
      float mnew = fmaxf(mrow[njq], mx);
      al[njq] = __expf(mrow[njq] - mnew);
      mrow[njq] = mnew;
      float rs = 0.f;
      int qq = w * 32 + njq * 16 + lrow;
#pragma unroll
      for (int mi = 0; mi < 4; ++mi) {
        f16x4 pw;
#pragma unroll
        for (int rr = 0; rr < 4; ++rr) {
          float p = __expf(s[mi][njq][rr] - mnew);
          rs += p;
          pw[rr] = (f16)p;
        }
        int slot = mi * 2 + (lk >> 1);
        *(f16x4*)(Ps + qq * 64 + ((slot ^ (qq & 7)) << 3) + ((lk & 1) << 2)) = pw;
      }
      rs += __shfl_xor(rs, 16);
      rs += __shfl_xor(rs, 32);
      lsum[njq] = lsum[njq] * al[njq] + rs;
    }

    // ---- rescale O: alpha lives at lanes (l&15)==q-local; O-lanes need
    //      q-local = lk*4+rr
#pragma unroll
    for (int njq = 0; njq < 2; ++njq) {
#pragma unroll
      for (int rr = 0; rr < 4; ++rr) {
        float a = __shfl(al[njq], lk * 4 + rr);
#pragma unroll
        for (int dj = 0; dj < 4; ++dj) O[njq][dj][rr] *= a;
      }
    }

    // raw s_barrier does NOT drain lgkmcnt: force Vt/Ps ds_writes visible
    asm volatile("s_waitcnt lgkmcnt(0)" ::: "memory");
    __builtin_amdgcn_s_barrier();  // bar2

    // ---- O += P @ V (16 MFMA)
#pragma unroll
    for (int kk = 0; kk < 2; ++kk) {
      int slotbase = kk * 4 + lk;
      f16x8 pa[2], vb[4];
#pragma unroll
      for (int njq = 0; njq < 2; ++njq) {
        int row = w * 32 + njq * 16 + lrow;
        pa[njq] = *(const f16x8*)(Ps + row * 64 + ((slotbase ^ (row & 7)) << 3));
      }
#pragma unroll
      for (int dj = 0; dj < 4; ++dj) {
        int d = dj * 16 + lrow;
        vb[dj] = *(const f16x8*)(Vt + d * 64 + ((slotbase ^ swzd(d)) << 3));
      }
#pragma unroll
      for (int njq = 0; njq < 2; ++njq)
#pragma unroll
        for (int dj = 0; dj < 4; ++dj)
          O[njq][dj] = mfma16(pa[njq], vb[dj], O[njq][dj]);
    }
  }

  // ---- epilogue
  float linv[2] = {1.f / lsum[0], 1.f / lsum[1]};
#pragma unroll
  for (int njq = 0; njq < 2; ++njq) {
#pragma unroll
    for (int rr = 0; rr < 4; ++rr) {
      float inv = __shfl(linv[njq], lk * 4 + rr);
      int qn = q0 + w * 32 + njq * 16 + lk * 4 + rr;
      size_t rowbase = ((size_t)(b * NSEQ + qn)) * KDIM + h * 64;
#pragma unroll
      for (int dj = 0; dj < 4; ++dj)
        aout[rowbase + dj * 16 + lrow] = (f16)(O[njq][dj][rr] * inv);
    }
  }
}

extern "C" void kernel_launch(void* const* d_in, const int* in_sizes, int n_in,
                              void* d_out, int out_size, void* d_ws, size_t ws_size,
                              hipStream_t stream) {
  const float* x = (const float*)d_in[0];
  const float* w_qkv = (const float*)d_in[1];
  const float* w_proj = (const float*)d_in[2];
  const float* log_decay = (const float*)d_in[3];

  f16* ws = (f16*)d_ws;
  f16* x16 = ws;
  f16* wq16 = x16 + (size_t)MROWS * KDIM;
  f16* wp16 = wq16 + (size_t)3 * KDIM * KDIM;
  f16* q16 = wp16 + (size_t)KDIM * KDIM;
  f16* k16 = q16 + (size_t)MROWS * KDIM;
  f16* v16 = k16 + (size_t)MROWS * KDIM;
  f16* a16 = v16 + (size_t)MROWS * KDIM;

  cvt_kernel<<<1024, 256, 0, stream>>>(x, w_qkv, w_proj, x16, wq16, wp16);
  qkv_gemm<<<dim3(12, 64), 256, 0, stream>>>(x16, wq16, q16, k16, v16);
  attn_f16<<<dim3(8, NH, 8), 256, 0, stream>>>(q16, k16, v16, log_decay, a16);
  proj_gemm<<<dim3(4, 64), 256, 0, stream>>>(a16, wp16, (float*)d_out);
}